// Round 2
// baseline (701.961 us; speedup 1.0000x reference)
//
#include <hip/hip_runtime.h>
#include <math.h>

// Problem shape (fixed by reference): B=32, T=4096, H=1024, fp32.
#define B_   32
#define T_   4096
#define H_   1024
#define H4_  256            // float4 per (b,t) row
#define G_   256            // pass-1 workgroups (1 per CU)
#define TPG_ (T_ / G_)      // 16 t per workgroup
#define BH4_ (B_ * H4_)     // 8192 float4 per t-slice / per output
#define NCHUNK_ 8           // combine: g-chunks
#define GPC_ (G_ / NCHUNK_) // 32 groups per chunk

// ---------------------------------------------------------------------------
// Pass 1: single-pass online-softmax attention, software-pipelined.
//
// vs the 700us baseline: that kernel drained vmcnt(0) at the dot and at TWO
// __syncthreads per t-step with 1 block/CU -> HBM idle during every reduce
// tail (~1.7 TB/s effective). Now:
//   - wave w owns b-rows {2w, 2w+1}; lane i reads float4 i+64j of a row, so
//     every global_load_dwordx4 covers one contiguous 1 KiB (ideal pattern)
//   - t+1 is prefetched into registers at the TOP of the iteration; the
//     loads stay in flight ACROSS a raw s_barrier (lgkmcnt-only fence,
//     ping-pong redw) and are consumed as late as possible after it
//   - current t's slice lives in LDS (128 KiB); each thread touches only its
//     own slots, so same-thread lgkm ordering suffices (no barrier for it)
//   - ONE barrier per t; no wave-0 serial phase (all threads read 16 floats)
// eh is read exactly once (512 MiB). Partials (m,l,O) written per group.
// VGPR ~115: s(32)+acc(32)+prefetch(32)+misc -> 16 waves/CU.
// ---------------------------------------------------------------------------
__global__ __launch_bounds__(1024) void flash_kernel(
    const float4* __restrict__ s4, const float4* __restrict__ eh4,
    float4* __restrict__ Og4, float* __restrict__ mg, float* __restrict__ lg)
{
    const int g    = blockIdx.x;
    const int tid  = threadIdx.x;
    const int lane = tid & 63;
    const int w    = tid >> 6;   // wave 0..15
    const int b0   = w * 2;      // wave's two b-rows
    const int b1   = b0 + 1;

    __shared__ float4 elds[B_ * H4_];            // 128 KiB current-t slice
    __shared__ __align__(16) float redw[2][16];  // ping-pong wave partials

    float4 sA[4], sB[4];
#pragma unroll
    for (int j = 0; j < 4; ++j) {
        sA[j] = s4[b0 * H4_ + lane + 64 * j];
        sB[j] = s4[b1 * H4_ + lane + 64 * j];
    }

    const float4* epA = eh4 + ((size_t)b0 * T_ + (size_t)g * TPG_) * H4_ + lane;
    const float4* epB = eh4 + ((size_t)b1 * T_ + (size_t)g * TPG_) * H4_ + lane;
    float4* slotA = &elds[b0 * H4_ + lane];      // own slots only
    float4* slotB = &elds[b1 * H4_ + lane];

    // ---- prologue: t=0 -> regs, dot, stash to LDS ----
    float pdot;
    {
        float4 eA[4], eB[4];
#pragma unroll
        for (int j = 0; j < 4; ++j) { eA[j] = epA[64 * j]; eB[j] = epB[64 * j]; }
        epA += H4_; epB += H4_;
        float p = 0.f;
#pragma unroll
        for (int j = 0; j < 4; ++j) {
            p += eA[j].x * sA[j].x + eA[j].y * sA[j].y
               + eA[j].z * sA[j].z + eA[j].w * sA[j].w;
            p += eB[j].x * sB[j].x + eB[j].y * sB[j].y
               + eB[j].z * sB[j].z + eB[j].w * sB[j].w;
        }
        pdot = p;
#pragma unroll
        for (int j = 0; j < 4; ++j) { slotA[64 * j] = eA[j]; slotB[64 * j] = eB[j]; }
    }

    float4 accA[4], accB[4];
#pragma unroll
    for (int j = 0; j < 4; ++j) {
        accA[j] = make_float4(0.f, 0.f, 0.f, 0.f);
        accB[j] = make_float4(0.f, 0.f, 0.f, 0.f);
    }
    float m = -INFINITY, l = 0.f;

    for (int t = 0; t < TPG_; ++t) {
        // issue next t's loads NOW; they stay in flight across the barrier
        float4 eA[4], eB[4];
        if (t < TPG_ - 1) {
#pragma unroll
            for (int j = 0; j < 4; ++j) { eA[j] = epA[64 * j]; eB[j] = epB[64 * j]; }
            epA += H4_; epB += H4_;
        }

        // block-reduce pdot -> score; ONE raw barrier, lgkm-only fence
        float q = pdot;
        for (int off = 32; off > 0; off >>= 1)
            q += __shfl_down(q, off, 64);
        if (lane == 0) redw[t & 1][w] = q;
        asm volatile("s_waitcnt lgkmcnt(0)" ::: "memory");
        __builtin_amdgcn_sched_barrier(0);
        __builtin_amdgcn_s_barrier();
        __builtin_amdgcn_sched_barrier(0);
        asm volatile("" ::: "memory");   // no LDS-read hoist above barrier

        const float4* rp = (const float4*)&redw[t & 1][0];
        float4 r0 = rp[0], r1 = rp[1], r2 = rp[2], r3 = rp[3];
        const float score = ((r0.x + r0.y) + (r0.z + r0.w))
                          + ((r1.x + r1.y) + (r1.z + r1.w))
                          + ((r2.x + r2.y) + (r2.z + r2.w))
                          + ((r3.x + r3.y) + (r3.z + r3.w));

        const float mn    = fmaxf(m, score);
        const float alpha = __expf(m - mn);      // first iter: exp(-inf)=0
        const float wgt   = __expf(score - mn);
        l = l * alpha + wgt;
        m = mn;

        // rescale + accumulate current t from LDS (own slots; no barrier)
#pragma unroll
        for (int j = 0; j < 4; ++j) {
            float4 vA = slotA[64 * j];
            accA[j].x = accA[j].x * alpha + wgt * vA.x;
            accA[j].y = accA[j].y * alpha + wgt * vA.y;
            accA[j].z = accA[j].z * alpha + wgt * vA.z;
            accA[j].w = accA[j].w * alpha + wgt * vA.w;
            float4 vB = slotB[64 * j];
            accB[j].x = accB[j].x * alpha + wgt * vB.x;
            accB[j].y = accB[j].y * alpha + wgt * vB.y;
            accB[j].z = accB[j].z * alpha + wgt * vB.z;
            accB[j].w = accB[j].w * alpha + wgt * vB.w;
        }

        // consume arrived prefetch as late as possible: dot for t+1, then
        // overwrite own LDS slots (reads of this t happened above)
        if (t < TPG_ - 1) {
            float p1 = 0.f;
#pragma unroll
            for (int j = 0; j < 4; ++j) {
                p1 += eA[j].x * sA[j].x + eA[j].y * sA[j].y
                    + eA[j].z * sA[j].z + eA[j].w * sA[j].w;
                p1 += eB[j].x * sB[j].x + eB[j].y * sB[j].y
                    + eB[j].z * sB[j].z + eB[j].w * sB[j].w;
            }
            pdot = p1;
#pragma unroll
            for (int j = 0; j < 4; ++j) { slotA[64 * j] = eA[j]; slotB[64 * j] = eB[j]; }
        }
    }

    float4* opA = Og4 + (size_t)g * BH4_ + b0 * H4_ + lane;
    float4* opB = Og4 + (size_t)g * BH4_ + b1 * H4_ + lane;
#pragma unroll
    for (int j = 0; j < 4; ++j) { opA[64 * j] = accA[j]; opB[64 * j] = accB[j]; }
    if (tid == 0) { mg[g] = m; lg[g] = l; }
}

// ---------------------------------------------------------------------------
// Pass 2a: weighted fold of 32 of the 256 group slabs per block.
// Grid 256 blocks x 256 thr: block = (oc 0..31, gc 0..7) -> 65536 threads,
// 8x the memory parallelism of the old 8192-thread combine. Weights
// exp(mg-M) (1/L applied in 2b) computed redundantly per block from mg
// (1 KiB, L2-hot).
// ---------------------------------------------------------------------------
__global__ __launch_bounds__(256) void combine_a(
    const float4* __restrict__ Og4, const float* __restrict__ mg,
    float4* __restrict__ p2)
{
    const int tid = threadIdx.x;
    const int oc  = blockIdx.x & 31;
    const int gc  = blockIdx.x >> 5;
    __shared__ float wsh[GPC_];
    __shared__ float red[4];

    // global max over the 256 group maxima (256 threads <-> 256 groups)
    float mv = mg[tid];
    float M = mv;
    for (int off = 32; off > 0; off >>= 1)
        M = fmaxf(M, __shfl_down(M, off, 64));
    if ((tid & 63) == 0) red[tid >> 6] = M;
    __syncthreads();
    M = fmaxf(fmaxf(red[0], red[1]), fmaxf(red[2], red[3]));
    __syncthreads();

    if (tid < GPC_) wsh[tid] = __expf(mg[gc * GPC_ + tid] - M);
    __syncthreads();

    const int o4 = oc * 256 + tid;
    const float4* src = Og4 + (size_t)(gc * GPC_) * BH4_ + o4;
    float4 acc = make_float4(0.f, 0.f, 0.f, 0.f);
#pragma unroll 8
    for (int gg = 0; gg < GPC_; ++gg) {
        float4 a = src[(size_t)gg * BH4_];
        float wv = wsh[gg];
        acc.x += wv * a.x; acc.y += wv * a.y;
        acc.z += wv * a.z; acc.w += wv * a.w;
    }
    p2[(size_t)gc * BH4_ + o4] = acc;
}

// ---------------------------------------------------------------------------
// Pass 2b: sum the 8 chunk partials, apply 1/L. 32 blocks x 256 thr.
// ---------------------------------------------------------------------------
__global__ __launch_bounds__(256) void combine_b(
    const float4* __restrict__ p2, const float* __restrict__ mg,
    const float* __restrict__ lg, float4* __restrict__ out4)
{
    const int tid = threadIdx.x;
    __shared__ float red[4];

    float mv = mg[tid];
    float M = mv;
    for (int off = 32; off > 0; off >>= 1)
        M = fmaxf(M, __shfl_down(M, off, 64));
    if ((tid & 63) == 0) red[tid >> 6] = M;
    __syncthreads();
    M = fmaxf(fmaxf(red[0], red[1]), fmaxf(red[2], red[3]));
    __syncthreads();

    float Ls = lg[tid] * __expf(mv - M);
    for (int off = 32; off > 0; off >>= 1)
        Ls += __shfl_down(Ls, off, 64);
    if ((tid & 63) == 0) red[tid >> 6] = Ls;
    __syncthreads();
    const float invL = 1.f / ((red[0] + red[1]) + (red[2] + red[3]));

    const int o4 = blockIdx.x * 256 + tid;
    float4 acc = make_float4(0.f, 0.f, 0.f, 0.f);
#pragma unroll
    for (int gc = 0; gc < NCHUNK_; ++gc) {
        float4 a = p2[(size_t)gc * BH4_ + o4];
        acc.x += a.x; acc.y += a.y; acc.z += a.z; acc.w += a.w;
    }
    out4[o4] = make_float4(acc.x * invL, acc.y * invL,
                           acc.z * invL, acc.w * invL);
}

extern "C" void kernel_launch(void* const* d_in, const int* in_sizes, int n_in,
                              void* d_out, int out_size, void* d_ws, size_t ws_size,
                              hipStream_t stream) {
    const float* s  = (const float*)d_in[0];   // [B, H]
    const float* eh = (const float*)d_in[1];   // [B, T, H]

    float4* Og4 = (float4*)d_ws;                                   // 32 MiB
    float*  mg  = (float*)((char*)d_ws + (size_t)G_ * BH4_ * 16);  // G_ floats
    float*  lg  = mg + G_;                                         // G_ floats
    float4* p2  = (float4*)((char*)d_ws + (size_t)G_ * BH4_ * 16 + 4096); // 1 MiB

    flash_kernel<<<G_, 1024, 0, stream>>>(
        (const float4*)s, (const float4*)eh, Og4, mg, lg);
    combine_a<<<G_, 256, 0, stream>>>(Og4, mg, p2);
    combine_b<<<BH4_ / 256, 256, 0, stream>>>(p2, mg, lg, (float4*)d_out);
}